// Round 7
// baseline (112.302 us; speedup 1.0000x reference)
//
#include <hip/hip_runtime.h>

#define EPS_F 1e-8f
#define BLOCK 256
#define EPT 2                      // elements per thread
#define ELEMS (BLOCK * EPT)        // 512 elements per block
#define SLAB_DW (ELEMS * 7)        // 3584 dwords per input slab
#define SLAB_CH (SLAB_DW / 4)      // 896 dwordx4 chunks per slab

typedef float vf4 __attribute__((ext_vector_type(4)));

__device__ __forceinline__ float fast_rcp(float x) {
    return __builtin_amdgcn_rcpf(x);  // v_rcp_f32, ~1 ulp
}

__global__ void zero_out_kernel(float* out) { out[0] = 0.f; }

// Edge (a->b) contribution to 2*signed-Area(P ∩ [-W,W]x[-H,H]) via the
// boundary integral of h(y)=clamp(y,-H,H)+H over the edge clipped to the
// x-slab (vertical closure segments have dx=0 -> 0). Split at y=±H
// crossings; trapezoid per piece exact. Branch-free, NaN-free.
__device__ __forceinline__ float edge_contrib(float ax, float ay,
                                              float bx, float by,
                                              float W, float H) {
    float dx = bx - ax, dy = by - ay;
    float sdx = (fabsf(dx) < 1e-20f) ? 1e-20f : dx;
    float sdy = (fabsf(dy) < 1e-20f) ? 1e-20f : dy;
    float rdx = fast_rcp(sdx);
    float rdy = fast_rcp(sdy);

    float tA = (-W - ax) * rdx;
    float tB = ( W - ax) * rdx;
    float ta = fmaxf(fminf(tA, tB), 0.f);
    float tb = fminf(fmaxf(tA, tB), 1.f);
    tb = fmaxf(ta, tb);

    float u0 = (-H - ay) * rdy;
    float u1 = ( H - ay) * rdy;
    float tm0 = fminf(u0, u1), tm1 = fmaxf(u0, u1);
    float t1 = fminf(fmaxf(tm0, ta), tb);
    float t2 = fminf(fmaxf(tm1, ta), tb);

    float x0 = fmaf(ta, dx, ax), y0 = fmaf(ta, dy, ay);
    float x1 = fmaf(t1, dx, ax), y1 = fmaf(t1, dy, ay);
    float x2 = fmaf(t2, dx, ax), y2 = fmaf(t2, dy, ay);
    float x3 = fmaf(tb, dx, ax), y3 = fmaf(tb, dy, ay);
    float h0 = fminf(fmaxf(y0, -H), H) + H;
    float h1 = fminf(fmaxf(y1, -H), H) + H;
    float h2 = fminf(fmaxf(y2, -H), H) + H;
    float h3 = fminf(fmaxf(y3, -H), H) + H;

    return (x1 - x0) * (h0 + h1) + (x2 - x1) * (h1 + h2) + (x3 - x2) * (h2 + h3);
}

__global__ __launch_bounds__(BLOCK, 4) void iou3d_loss_kernel(
    const float* __restrict__ pred, const float* __restrict__ target,
    const float* __restrict__ weight, float* __restrict__ out,
    int N, float invN)
{
    const int tid = threadIdx.x;

    // ---- phase 0: dense stride-1 staging of pred+target slabs into LDS ----
    // Each wave-instruction is a fully-coalesced dwordx4 over 16 cache lines
    // (the 6.3 TB/s copy-benchmark pattern). 7 chunks/thread, branchless.
    __shared__ vf4 lds4[2 * SLAB_CH];            // 28 KB
    const float* ldsf = (const float*)lds4;

    long blk_dw = (long)blockIdx.x * SLAB_DW;    // block's slab start (dwords)
    long maxdw  = (long)N * 7 - 4;               // last valid chunk start
    #pragma unroll
    for (int k = 0; k < 7; ++k) {
        int c = k * BLOCK + tid;                 // 0 .. 1791
        bool isT = (c >= SLAB_CH);
        int  cl  = isT ? c - SLAB_CH : c;
        long gdw = blk_dw + (long)cl * 4;
        gdw = (gdw > maxdw) ? maxdw : gdw;
        const float* src = isT ? target : pred;
        vf4 v;
        __builtin_memcpy(&v, src + gdw, 16);     // global_load_dwordx4
        lds4[c] = v;                             // ds_write_b128 (16B aligned)
    }

    // weight: dense stride-1 dword load, hoisted to overlap staging
    float wgt[EPT];
    int ibase = blockIdx.x * ELEMS + tid;
    #pragma unroll
    for (int e = 0; e < EPT; ++e) {
        int i = ibase + e * BLOCK;
        int j = (i < N) ? i : N - 1;
        wgt[e] = (i < N) ? weight[j] : 0.f;
    }

    __syncthreads();

    // ---- phase 1+2: read records from LDS, compute ----
    // LDS read stride 7 dwords: gcd(7,32)=1 -> all banks, 2-way/wave64 (free)
    float val = 0.f;
    #pragma unroll
    for (int e = 0; e < EPT; ++e) {
        int el = e * BLOCK + tid;                // local element index
        const float* p = ldsf + 7 * el;          // pred record
        const float* q = ldsf + SLAB_DW + 7 * el;// target record
        float a0 = p[0], a1 = p[1], a2 = p[2], a3 = p[3], a4 = p[4], a5 = p[5], a6 = p[6];
        float b0 = q[0], b1_ = q[1], b2_ = q[2], b3 = q[3], b4 = q[4], b5 = q[5], b6 = q[6];

        float s1, c1, s2, c2;
        __sincosf(a6, &s1, &c1);
        __sincosf(b6, &s2, &c2);
        float cd = c1 * c2 + s1 * s2;            // cos(a2-a1)
        float sd = c1 * s2 - s1 * c2;            // sin(a2-a1)
        float dxc = b0 - a0, dyc = b1_ - a1;
        float tx =  c1 * dxc + s1 * dyc;
        float ty = -s1 * dxc + c1 * dyc;
        float W = 0.5f * a3, H = 0.5f * a4;
        float w2 = 0.5f * b3, h2 = 0.5f * b4;

        // box2 corners in box1 frame (CCW)
        float cw = cd * w2, sw = sd * w2, ch = cd * h2, sh = sd * h2;
        float q0x =  cw - sh + tx, q0y =  sw + ch + ty;
        float q1x = -cw - sh + tx, q1y = -sw + ch + ty;
        float q2x = -cw + sh + tx, q2y = -sw - ch + ty;
        float q3x =  cw + sh + tx, q3y =  sw - ch + ty;

        float s  = edge_contrib(q0x, q0y, q1x, q1y, W, H)
                 + edge_contrib(q1x, q1y, q2x, q2y, W, H)
                 + edge_contrib(q2x, q2y, q3x, q3y, W, H)
                 + edge_contrib(q3x, q3y, q0x, q0y, W, H);
        float area = 0.5f * fabsf(s);

        float zmax = fminf(a2 + 0.5f * a5, b2_ + 0.5f * b5);
        float zmin = fmaxf(a2 - 0.5f * a5, b2_ - 0.5f * b5);
        float inter3d = area * fmaxf(zmax - zmin, 0.f);
        float v1 = a3 * a4 * a5;
        float v2 = b3 * b4 * b5;
        float iou = inter3d * fast_rcp(v1 + v2 - inter3d + EPS_F);
        val += (1.f - iou) * wgt[e];
    }

    // ---- reduction: wave64 shuffle -> LDS -> one atomic per block ----
    #pragma unroll
    for (int off = 32; off > 0; off >>= 1) val += __shfl_down(val, off, 64);
    __shared__ float wsum[4];
    int lane = tid & 63, wid = tid >> 6;
    if (lane == 0) wsum[wid] = val;
    __syncthreads();
    if (tid == 0) {
        float ssum = (wsum[0] + wsum[1] + wsum[2] + wsum[3]) * invN;
        atomicAdd(out, ssum);
    }
}

extern "C" void kernel_launch(void* const* d_in, const int* in_sizes, int n_in,
                              void* d_out, int out_size, void* d_ws, size_t ws_size,
                              hipStream_t stream) {
    const float* pred   = (const float*)d_in[0];
    const float* target = (const float*)d_in[1];
    const float* weight = (const float*)d_in[2];
    float* out = (float*)d_out;
    int N = in_sizes[2];  // weight element count

    zero_out_kernel<<<1, 1, 0, stream>>>(out);
    int grid = (N + ELEMS - 1) / ELEMS;
    iou3d_loss_kernel<<<grid, BLOCK, 0, stream>>>(pred, target, weight, out,
                                                  N, 1.f / (float)N);
}